// Round 1
// baseline (875.078 us; speedup 1.0000x reference)
//
#include <hip/hip_runtime.h>

// AudioStructuralAnalyzer fused kernel.
// One block = one 32x32 output tile of one batch image; loops over C=2 channels,
// accumulating the channel mean in registers. All intermediate fields staged in LDS.
//
// Halo bookkeeping (tile coords, output pixel p):
//   curvature(p) <- gauss5(curv) : curv on halo 2
//   curv(q)      <- sobel(ux,uy) : ux,uy on halo 3
//   ux(r)        <- sobel(x)     : x on halo 4
//   harmonic     <- x rows +-3   : covered by x halo 4
// Conv zero-padding applies per FIELD: halo cells outside the image are zeroed
// per-field (not computed from padded x), matching jax.lax.conv zero padding.

#define F_DIM 256
#define T_DIM 2048
#define B_DIM 8
#define C_DIM 2
#define TILE  32
#define XH 4
#define XN (TILE + 2*XH)   // 40
#define XS (XN + 1)        // 41 (odd stride: no LDS bank conflicts)
#define UH 3
#define UN (TILE + 2*UH)   // 38
#define US (UN + 1)        // 39
#define FH 2
#define FN (TILE + 2*FH)   // 36
#define FS (FN + 1)        // 37
#define EPSF 1e-10f

__global__ __launch_bounds__(256, 3)
void audio_struct_fused(const float* __restrict__ x_in,
                        const float* __restrict__ gk_in,
                        float* __restrict__ out)
{
    __shared__ float s_x  [XN*XS];   // raw input tile (zero OOB)
    __shared__ float s_ux [UN*US];   // cos(angle)
    __shared__ float s_uy [UN*US];   // sin(angle)
    __shared__ float s_sxx[FN*FS];   // vx*vx
    __shared__ float s_syy[FN*FS];   // vy*vy
    __shared__ float s_sxy[FN*FS];   // vx*vy
    __shared__ float s_tin[FN*FS];   // 1/(1+|grad_time|)
    __shared__ float s_sf [FN*FS];   // |grad_freq|
    __shared__ float s_cv [FN*FS];   // curv
    __shared__ float s_gk [25];

    const int tx  = threadIdx.x;          // 0..31 (time)
    const int ty  = threadIdx.y;          // 0..7  (freq)
    const int tid = ty * 32 + tx;
    const int t0  = blockIdx.x * TILE;
    const int f0  = blockIdx.y * TILE;
    const int b   = blockIdx.z;

    if (tid < 25) s_gk[tid] = gk_in[tid];

    float acc[6][4];
    #pragma unroll
    for (int k = 0; k < 6; ++k)
        #pragma unroll
        for (int s = 0; s < 4; ++s) acc[k][s] = 0.0f;

    for (int c = 0; c < C_DIM; ++c) {
        __syncthreads();   // protect LDS reuse across channels; also fences s_gk init

        // ---- Phase A: load x tile + halo 4, zero outside the image ----
        const float* xp = x_in + (size_t)(b * C_DIM + c) * F_DIM * T_DIM;
        for (int idx = tid; idx < XN * XN; idx += 256) {
            int r  = idx / XN, cc = idx % XN;
            int gf = f0 + r - XH, gt = t0 + cc - XH;
            float v = 0.0f;
            if ((unsigned)gf < (unsigned)F_DIM && (unsigned)gt < (unsigned)T_DIM)
                v = xp[gf * T_DIM + gt];
            s_x[r * XS + cc] = v;
        }
        __syncthreads();

        // ---- Phase B: ux/uy on 38x38 (halo 3); pointwise fields on 36x36 ----
        for (int idx = tid; idx < UN * UN; idx += 256) {
            int r = idx / UN, cc = idx % UN;
            int gfr = f0 + r - UH, gtc = t0 + cc - UH;
            float ux = 0.f, uy = 0.f, sxx = 0.f, syy = 0.f, sxy = 0.f,
                  tin = 0.f, sf = 0.f;
            if ((unsigned)gfr < (unsigned)F_DIM && (unsigned)gtc < (unsigned)T_DIM) {
                const float* xc = &s_x[(r + 1) * XS + (cc + 1)];
                float x00 = xc[-XS-1], x01 = xc[-XS], x02 = xc[-XS+1];
                float x10 = xc[-1],                  x12 = xc[1];
                float x20 = xc[XS-1],  x21 = xc[XS],  x22 = xc[XS+1];
                // cross-correlation (XLA conv does not flip kernels)
                float gfv = ((x20 + 2.f*x21 + x22) - (x00 + 2.f*x01 + x02)) * 0.125f;
                float gtv = ((x02 + 2.f*x12 + x22) - (x00 + 2.f*x10 + x20)) * 0.125f;
                float gte = gtv + EPSF;
                float rh  = rsqrtf(gfv * gfv + gte * gte);
                ux = gte * rh;                 // cos(atan2(gf, gt+eps))
                uy = gfv * rh;                 // sin(atan2(gf, gt+eps))
                float mag = sqrtf(gfv * gfv + gtv * gtv + EPSF);
                float vx = mag * ux, vy = mag * uy;
                sxx = vx * vx; syy = vy * vy; sxy = vx * vy;
                tin = 1.0f / (1.0f + fabsf(gtv));
                sf  = fabsf(gfv);
            }
            s_ux[r * US + cc] = ux;
            s_uy[r * US + cc] = uy;
            if (r >= 1 && r < UN - 1 && cc >= 1 && cc < UN - 1) {
                int fi = (r - 1) * FS + (cc - 1);
                s_sxx[fi] = sxx; s_syy[fi] = syy; s_sxy[fi] = sxy;
                s_tin[fi] = tin; s_sf[fi]  = sf;
            }
        }
        __syncthreads();

        // ---- Phase C: curv on 36x36 (sobel of ux/uy, zero-padded fields) ----
        for (int idx = tid; idx < FN * FN; idx += 256) {
            int r = idx / FN, cc = idx % FN;
            int gfr = f0 + r - FH, gtc = t0 + cc - FH;
            float cv = 0.0f;
            if ((unsigned)gfr < (unsigned)F_DIM && (unsigned)gtc < (unsigned)T_DIM) {
                const float* up = &s_ux[(r + 1) * US + (cc + 1)];
                const float* vp = &s_uy[(r + 1) * US + (cc + 1)];
                float u00 = up[-US-1], u01 = up[-US], u02 = up[-US+1];
                float u10 = up[-1],                  u12 = up[1];
                float u20 = up[US-1],  u21 = up[US],  u22 = up[US+1];
                float dudx = ((u02 + 2.f*u12 + u22) - (u00 + 2.f*u10 + u20)) * 0.125f;
                float dudy = ((u20 + 2.f*u21 + u22) - (u00 + 2.f*u01 + u02)) * 0.125f;
                float v00 = vp[-US-1], v01 = vp[-US], v02 = vp[-US+1];
                float v10 = vp[-1],                  v12 = vp[1];
                float v20 = vp[US-1],  v21 = vp[US],  v22 = vp[US+1];
                float dvdx = ((v02 + 2.f*v12 + v22) - (v00 + 2.f*v10 + v20)) * 0.125f;
                float dvdy = ((v20 + 2.f*v21 + v22) - (v00 + 2.f*v01 + v02)) * 0.125f;
                cv = sqrtf(dudx*dudx + dudy*dudy + dvdx*dvdx + dvdy*dvdy + EPSF);
            }
            s_cv[r * FS + cc] = cv;
        }
        __syncthreads();

        // ---- Phase D: nine 25-tap gaussians + pointwise epilogue ----
        #pragma unroll
        for (int s = 0; s < 4; ++s) {
            const int ry = ty + 8 * s;        // output row in tile
            float vxx = 0.f, vyy = 0.f, vxy = 0.f, ua = 0.f, va = 0.f,
                  cvs = 0.f, le = 0.f, tp = 0.f, sp = 0.f;
            for (int i = 0; i < 5; ++i) {
                const int fb = (ry + i) * FS + tx;          // field bufs (halo 2)
                const int ub = (ry + i + 1) * US + tx + 1;  // ux/uy (halo 3)
                const int xb = (ry + i + 2) * XS + tx + 2;  // x (halo 4)
                #pragma unroll
                for (int j = 0; j < 5; ++j) {
                    float g = s_gk[i * 5 + j];
                    vxx += g * s_sxx[fb + j];
                    vyy += g * s_syy[fb + j];
                    vxy += g * s_sxy[fb + j];
                    ua  += g * s_ux [ub + j];
                    va  += g * s_uy [ub + j];
                    cvs += g * s_cv [fb + j];
                    tp  += g * s_tin[fb + j];
                    sp  += g * s_sf [fb + j];
                    float xv = s_x[xb + j];
                    le  += g * xv * xv;
                }
            }
            // entropy (cancellation-free discriminant: trace^2-4det = (a-d)^2+4b^2)
            float trace = vxx + vyy;
            float diff  = vxx - vyy;
            float disc  = sqrtf(fmaxf(diff * diff + 4.f * vxy * vxy, 0.f) + EPSF);
            float l1 = fmaxf(0.5f * (trace + disc), EPSF);
            float l2 = fmaxf(0.5f * (trace - disc), EPSF);
            float ssum = l1 + l2 + EPSF;
            float p1 = l1 / ssum, p2 = l2 / ssum;
            float ent = -(p1 * logf(p1 + EPSF) + p2 * logf(p2 + EPSF)) * 1.44269504088896340736f;
            ent = fminf(fmaxf(ent, 0.f), 1.f);
            // alignment
            float align = fminf(sqrtf(ua * ua + va * va + EPSF), 1.f);
            // harmonic: |-x[f-3] + 2x[f] - x[f+3]| / (gauss(x^2) + eps)
            float xm  = s_x[(ry + 1) * XS + tx + 4];
            float x0v = s_x[(ry + 4) * XS + tx + 4];
            float xpv = s_x[(ry + 7) * XS + tx + 4];
            float harm = fabsf(2.f * x0v - xm - xpv);
            float hm = fminf(fmaxf(harm / (le + EPSF), 0.f), 1.f);
            float tpv = fminf(fmaxf(tp, 0.f), 1.f);
            float spv = fminf(fmaxf(sp, 0.f), 1.f);

            acc[0][s] += 0.5f * ent;
            acc[1][s] += 0.5f * align;
            acc[2][s] += 0.5f * cvs;
            acc[3][s] += 0.5f * hm;
            acc[4][s] += 0.5f * tpv;
            acc[5][s] += 0.5f * spv;
        }
    }

    // ---- write 6 output planes, coalesced ----
    const size_t plane = (size_t)B_DIM * F_DIM * T_DIM;
    const size_t base  = (size_t)b * F_DIM * T_DIM + (size_t)f0 * T_DIM + t0 + tx;
    #pragma unroll
    for (int k = 0; k < 6; ++k)
        #pragma unroll
        for (int s = 0; s < 4; ++s) {
            int ry = ty + 8 * s;
            out[k * plane + base + (size_t)(f0 >= 0 ? ry : 0) * T_DIM] = acc[k][s];
        }
}

extern "C" void kernel_launch(void* const* d_in, const int* in_sizes, int n_in,
                              void* d_out, int out_size, void* d_ws, size_t ws_size,
                              hipStream_t stream) {
    const float* x  = (const float*)d_in[0];
    const float* gk = (const float*)d_in[1];
    float* out = (float*)d_out;
    dim3 grid(T_DIM / TILE, F_DIM / TILE, B_DIM);   // 64 x 8 x 8 = 4096 blocks
    dim3 block(32, 8);                              // 256 threads = 4 waves
    audio_struct_fused<<<grid, block, 0, stream>>>(x, gk, out);
}

// Round 2
// 248.918 us; speedup vs baseline: 3.5155x; 3.5155x over previous
//
#include <hip/hip_runtime.h>
#include <hip/hip_fp16.h>

// AudioStructuralAnalyzer fused kernel, round 2.
// Key changes vs round 1:
//  - separable 5x5 gaussian (1D weights = normalized middle row of the 2D kernel)
//  - all intermediate fields packed as half2 pairs in LDS: (sxx,syy), (sxy,tin),
//    (sf,cv), (ux,uy); x^2/le computed on the fly from s_x
//  - LDS 50.7KB -> 32.6KB => 5 blocks/CU; launch_bounds(256,4) for VGPR headroom

#define F_DIM 256
#define T_DIM 2048
#define B_DIM 8
#define C_DIM 2
#define TILE  32

#define XROWS 40          // x tile: halo 4
#define XS    42          // even stride -> 8B-aligned rows for float2 LDS writes
#define UROWS 38          // (ux,uy): halo 3
#define US    38
#define FROWS 36          // field pairs: halo 2
#define FS    36
#define TS    36          // vertical-pass tmp stride
#define EPSF  1e-10f

__global__ __launch_bounds__(256, 4)
void audio_struct_fused(const float* __restrict__ x_in,
                        const float* __restrict__ gk_in,
                        float* __restrict__ out)
{
    __shared__ float   s_x [XROWS*XS];    // 6720 B  raw input (zero OOB)
    __shared__ __half2 s_u [UROWS*US];    // 5776 B  (ux, uy)
    __shared__ __half2 s_P0[FROWS*FS];    // 5184 B  (sxx, syy)
    __shared__ __half2 s_P1[FROWS*FS];    // 5184 B  (sxy, tin)
    __shared__ __half2 s_P2[FROWS*FS];    // 5184 B  (sf,  cv)   cv written in Phase C
    __shared__ __half2 s_tmp[TILE*TS];    // 4608 B  vertical-pass ping-pong

    const int tx  = threadIdx.x;          // 0..31 (time)
    const int ty  = threadIdx.y;          // 0..7  (freq)
    const int tid = ty * 32 + tx;
    const int t0  = blockIdx.x * TILE;
    const int f0  = blockIdx.y * TILE;
    const int b   = blockIdx.z;

    // 1D gaussian weights: normalized middle row of the (separable) 5x5 kernel.
    // w_i*w_j == gk2d[i][j] exactly (outer-product kernel).
    float r0 = gk_in[10], r1 = gk_in[11], r2 = gk_in[12], r3 = gk_in[13], r4 = gk_in[14];
    float winv = 1.0f / (r0 + r1 + r2 + r3 + r4);
    const float w[5] = {r0*winv, r1*winv, r2*winv, r3*winv, r4*winv};

    float acc[6][4];
    #pragma unroll
    for (int k = 0; k < 6; ++k)
        #pragma unroll
        for (int s = 0; s < 4; ++s) acc[k][s] = 0.0f;

    for (int c = 0; c < C_DIM; ++c) {
        __syncthreads();   // protect LDS reuse across channel iterations

        // ---- Phase A: load x tile + halo 4 as float2 (pairs never straddle edges) ----
        const float* xp = x_in + (size_t)(b * C_DIM + c) * F_DIM * T_DIM;
        for (int idx = tid; idx < XROWS * 20; idx += 256) {
            int r  = idx / 20, c2 = idx % 20;
            int gf = f0 + r - 4;
            int gt = t0 + c2 * 2 - 4;          // even => 8B aligned, never straddles 0/2048
            float2 v = make_float2(0.f, 0.f);
            if ((unsigned)gf < (unsigned)F_DIM && (unsigned)gt < (unsigned)T_DIM)
                v = *(const float2*)(xp + (size_t)gf * T_DIM + gt);
            *(float2*)&s_x[r * XS + c2 * 2] = v;
        }
        __syncthreads();

        // ---- Phase B: (ux,uy) on 38x38; packed pointwise fields on 36x36 ----
        for (int idx = tid; idx < UROWS * UROWS; idx += 256) {
            int r = idx / UROWS, cc = idx % UROWS;
            int gfr = f0 + r - 3, gtc = t0 + cc - 3;
            float ux = 0.f, uy = 0.f, sxx = 0.f, syy = 0.f, sxy = 0.f,
                  tin = 0.f, sf = 0.f;
            if ((unsigned)gfr < (unsigned)F_DIM && (unsigned)gtc < (unsigned)T_DIM) {
                const float* xc = &s_x[(r + 1) * XS + (cc + 1)];
                float x00 = xc[-XS-1], x01 = xc[-XS], x02 = xc[-XS+1];
                float x10 = xc[-1],                   x12 = xc[1];
                float x20 = xc[XS-1],  x21 = xc[XS],  x22 = xc[XS+1];
                // cross-correlation (XLA conv does not flip kernels)
                float gfv = ((x20 + 2.f*x21 + x22) - (x00 + 2.f*x01 + x02)) * 0.125f;
                float gtv = ((x02 + 2.f*x12 + x22) - (x00 + 2.f*x10 + x20)) * 0.125f;
                float gte = gtv + EPSF;
                float rh  = rsqrtf(gfv * gfv + gte * gte);
                ux = gte * rh;                 // cos(atan2(gf, gt+eps))
                uy = gfv * rh;                 // sin(atan2(gf, gt+eps))
                float mag2 = gfv * gfv + gtv * gtv + EPSF;
                float m2h  = mag2 * rh;        // mag^2 / hyp
                float vx = m2h * ux * rh;      // (mag/hyp)^2 * ... keep exact form below
                // exact: vx = mag*ux, vy = mag*uy with mag = sqrt(mag2)
                float mag = sqrtf(mag2);
                vx = mag * ux; float vy = mag * uy;
                sxx = vx * vx; syy = vy * vy; sxy = vx * vy;
                tin = 1.0f / (1.0f + fabsf(gtv));
                sf  = fabsf(gfv);
            }
            s_u[r * US + cc] = __floats2half2_rn(ux, uy);
            if (r >= 1 && r < UROWS - 1 && cc >= 1 && cc < UROWS - 1) {
                int fi = (r - 1) * FS + (cc - 1);
                s_P0[fi] = __floats2half2_rn(sxx, syy);
                s_P1[fi] = __floats2half2_rn(sxy, tin);
                s_P2[fi] = __floats2half2_rn(sf, 0.f);   // .y = cv, filled in Phase C
            }
        }
        __syncthreads();

        // ---- Phase C: curv on 36x36 (sobel of ux/uy), write into s_P2.y ----
        for (int idx = tid; idx < FROWS * FROWS; idx += 256) {
            int r = idx / FROWS, cc = idx % FROWS;
            int gfr = f0 + r - 2, gtc = t0 + cc - 2;
            float cv = 0.0f;
            if ((unsigned)gfr < (unsigned)F_DIM && (unsigned)gtc < (unsigned)T_DIM) {
                // field (r,cc) is u (r+1, cc+1); 3x3 neighborhood = u rows r..r+2
                const __half2* up = &s_u[r * US + cc];
                float2 u00 = __half22float2(up[0]),      u01 = __half22float2(up[1]),      u02 = __half22float2(up[2]);
                float2 u10 = __half22float2(up[US]),                                      u12 = __half22float2(up[US+2]);
                float2 u20 = __half22float2(up[2*US]),   u21 = __half22float2(up[2*US+1]), u22 = __half22float2(up[2*US+2]);
                float dudx = ((u02.x + 2.f*u12.x + u22.x) - (u00.x + 2.f*u10.x + u20.x)) * 0.125f;
                float dudy = ((u20.x + 2.f*u21.x + u22.x) - (u00.x + 2.f*u01.x + u02.x)) * 0.125f;
                float dvdx = ((u02.y + 2.f*u12.y + u22.y) - (u00.y + 2.f*u10.y + u20.y)) * 0.125f;
                float dvdy = ((u20.y + 2.f*u21.y + u22.y) - (u00.y + 2.f*u01.y + u02.y)) * 0.125f;
                cv = sqrtf(dudx*dudx + dudy*dudy + dvdx*dvdx + dvdy*dvdy + EPSF);
            }
            ((__half*)s_P2)[2 * (r * FS + cc) + 1] = __float2half_rn(cv);
        }
        __syncthreads();

        // ================= Phase D: separable gaussians, 5 paired jobs =================
        float vxx[4], vyy[4], le[4];

        // ---- job 0: (sxx,syy) -> vxx,vyy (kept for job 1 epilogue) ----
        for (int idx = tid; idx < TILE * FS; idx += 256) {
            int r = idx / FS, cc = idx % FS;
            float a = 0.f, bv = 0.f;
            #pragma unroll
            for (int i = 0; i < 5; ++i) {
                float2 v = __half22float2(s_P0[(r + i) * FS + cc]);
                a += w[i] * v.x; bv += w[i] * v.y;
            }
            s_tmp[r * TS + cc] = __floats2half2_rn(a, bv);
        }
        __syncthreads();
        #pragma unroll
        for (int s = 0; s < 4; ++s) {
            int ry = ty + 8 * s;
            float a = 0.f, bv = 0.f;
            #pragma unroll
            for (int j = 0; j < 5; ++j) {
                float2 v = __half22float2(s_tmp[ry * TS + tx + j]);
                a += w[j] * v.x; bv += w[j] * v.y;
            }
            vxx[s] = a; vyy[s] = bv;
        }
        __syncthreads();

        // ---- job 1: (sxy,tin) -> entropy + temporal ----
        for (int idx = tid; idx < TILE * FS; idx += 256) {
            int r = idx / FS, cc = idx % FS;
            float a = 0.f, bv = 0.f;
            #pragma unroll
            for (int i = 0; i < 5; ++i) {
                float2 v = __half22float2(s_P1[(r + i) * FS + cc]);
                a += w[i] * v.x; bv += w[i] * v.y;
            }
            s_tmp[r * TS + cc] = __floats2half2_rn(a, bv);
        }
        __syncthreads();
        #pragma unroll
        for (int s = 0; s < 4; ++s) {
            int ry = ty + 8 * s;
            float vxy = 0.f, tp = 0.f;
            #pragma unroll
            for (int j = 0; j < 5; ++j) {
                float2 v = __half22float2(s_tmp[ry * TS + tx + j]);
                vxy += w[j] * v.x; tp += w[j] * v.y;
            }
            float trace = vxx[s] + vyy[s];
            float diff  = vxx[s] - vyy[s];
            float disc  = sqrtf(fmaxf(diff * diff + 4.f * vxy * vxy, 0.f) + EPSF);
            float l1 = fmaxf(0.5f * (trace + disc), EPSF);
            float l2 = fmaxf(0.5f * (trace - disc), EPSF);
            float ssum = l1 + l2 + EPSF;
            float p1 = l1 / ssum, p2 = l2 / ssum;
            float ent = -(p1 * logf(p1 + EPSF) + p2 * logf(p2 + EPSF)) * 1.44269504088896340736f;
            acc[0][s] += 0.5f * fminf(fmaxf(ent, 0.f), 1.f);
            acc[4][s] += 0.5f * fminf(fmaxf(tp, 0.f), 1.f);
        }
        __syncthreads();

        // ---- job 2: (sf,cv) -> spectral + curvature ----
        for (int idx = tid; idx < TILE * FS; idx += 256) {
            int r = idx / FS, cc = idx % FS;
            float a = 0.f, bv = 0.f;
            #pragma unroll
            for (int i = 0; i < 5; ++i) {
                float2 v = __half22float2(s_P2[(r + i) * FS + cc]);
                a += w[i] * v.x; bv += w[i] * v.y;
            }
            s_tmp[r * TS + cc] = __floats2half2_rn(a, bv);
        }
        __syncthreads();
        #pragma unroll
        for (int s = 0; s < 4; ++s) {
            int ry = ty + 8 * s;
            float sp = 0.f, cvs = 0.f;
            #pragma unroll
            for (int j = 0; j < 5; ++j) {
                float2 v = __half22float2(s_tmp[ry * TS + tx + j]);
                sp += w[j] * v.x; cvs += w[j] * v.y;
            }
            acc[5][s] += 0.5f * fminf(fmaxf(sp, 0.f), 1.f);
            acc[2][s] += 0.5f * cvs;
        }
        __syncthreads();

        // ---- job 3: (ux,uy) -> alignment (reads s_u directly, halo-3 offsets) ----
        for (int idx = tid; idx < TILE * FS; idx += 256) {
            int r = idx / FS, cc = idx % FS;
            float a = 0.f, bv = 0.f;
            #pragma unroll
            for (int i = 0; i < 5; ++i) {
                float2 v = __half22float2(s_u[(r + i + 1) * US + (cc + 1)]);
                a += w[i] * v.x; bv += w[i] * v.y;
            }
            s_tmp[r * TS + cc] = __floats2half2_rn(a, bv);
        }
        __syncthreads();
        #pragma unroll
        for (int s = 0; s < 4; ++s) {
            int ry = ty + 8 * s;
            float ua = 0.f, va = 0.f;
            #pragma unroll
            for (int j = 0; j < 5; ++j) {
                float2 v = __half22float2(s_tmp[ry * TS + tx + j]);
                ua += w[j] * v.x; va += w[j] * v.y;
            }
            acc[1][s] += 0.5f * fminf(sqrtf(ua * ua + va * va + EPSF), 1.f);
        }
        __syncthreads();

        // ---- job 4: le = gauss(x^2) on the fly from s_x (halo-4 offsets), scalar half ----
        {
            __half* t1 = (__half*)s_tmp;
            for (int idx = tid; idx < TILE * FS; idx += 256) {
                int r = idx / FS, cc = idx % FS;
                float a = 0.f;
                #pragma unroll
                for (int i = 0; i < 5; ++i) {
                    float xv = s_x[(r + i + 2) * XS + (cc + 2)];
                    a += w[i] * xv * xv;
                }
                t1[r * TS + cc] = __float2half_rn(a);
            }
            __syncthreads();
            #pragma unroll
            for (int s = 0; s < 4; ++s) {
                int ry = ty + 8 * s;
                float a = 0.f;
                #pragma unroll
                for (int j = 0; j < 5; ++j)
                    a += w[j] * __half2float(t1[ry * TS + tx + j]);
                le[s] = a;
            }
        }
        // harmonic epilogue: |2x[f] - x[f-3] - x[f+3]| / (le + eps)
        #pragma unroll
        for (int s = 0; s < 4; ++s) {
            int ry = ty + 8 * s;
            float xm  = s_x[(ry + 1) * XS + tx + 4];
            float x0v = s_x[(ry + 4) * XS + tx + 4];
            float xpv = s_x[(ry + 7) * XS + tx + 4];
            float harm = fabsf(2.f * x0v - xm - xpv);
            acc[3][s] += 0.5f * fminf(fmaxf(harm / (le[s] + EPSF), 0.f), 1.f);
        }
        // loop-top __syncthreads() protects s_tmp/s_x reuse for channel 1
    }

    // ---- write 6 output planes, coalesced rows of 128B per wave-row ----
    const size_t plane = (size_t)B_DIM * F_DIM * T_DIM;
    const size_t base  = (size_t)b * F_DIM * T_DIM + (size_t)f0 * T_DIM + t0 + tx;
    #pragma unroll
    for (int k = 0; k < 6; ++k)
        #pragma unroll
        for (int s = 0; s < 4; ++s)
            out[k * plane + base + (size_t)(ty + 8 * s) * T_DIM] = acc[k][s];
}

extern "C" void kernel_launch(void* const* d_in, const int* in_sizes, int n_in,
                              void* d_out, int out_size, void* d_ws, size_t ws_size,
                              hipStream_t stream) {
    const float* x  = (const float*)d_in[0];
    const float* gk = (const float*)d_in[1];
    float* out = (float*)d_out;
    dim3 grid(T_DIM / TILE, F_DIM / TILE, B_DIM);   // 64 x 8 x 8 = 4096 blocks
    dim3 block(32, 8);                              // 256 threads = 4 waves
    audio_struct_fused<<<grid, block, 0, stream>>>(x, gk, out);
}

// Round 3
// 225.186 us; speedup vs baseline: 3.8860x; 1.1054x over previous
//
#include <hip/hip_runtime.h>
#include <hip/hip_fp16.h>

// AudioStructuralAnalyzer fused kernel, round 3.
// vs round 2:
//  - packed v_pk_fma_f16 in all separable-gaussian passes; paired uint2 LDS
//    reads in vertical passes (2 elems / ds_read_b64, no div in the loop)
//  - entropy path stores (trace, diff) pre-quantization (linearity of gauss)
//    to kill the vxx-vyy cancellation under f16
//  - hardware transcendentals: v_log_f32 (=log2, matches the /ln2 in the ref),
//    v_rcp_f32, v_rsq_f32, v_sqrt_f32, v_cvt_pkrtz
//  - job k horizontal pass fused with job k+1 vertical pass into dead buffers:
//    9 __syncthreads per channel instead of 14; LDS unchanged (5 blocks/CU)

#define F_DIM 256
#define T_DIM 2048
#define B_DIM 8
#define C_DIM 2
#define TILE  32

#define XROWS 40          // x tile: halo 4
#define XS    42
#define UROWS 38          // (ux,uy): halo 3
#define US    38
#define FROWS 36          // field tiles: halo 2
#define FS    36
#define FH2   18          // FS/2 uint2 pairs per row
#define EPSF  1e-10f

static __device__ __forceinline__ __half2 pack_h2(float a, float b) {
    auto v = __builtin_amdgcn_cvt_pkrtz(a, b);   // v_cvt_pkrtz_f16_f32, 1 inst
    return *(__half2*)&v;
}
static __device__ __forceinline__ float clamp01(float x) {
    return fminf(fmaxf(x, 0.f), 1.f);
}

__global__ __launch_bounds__(256, 4)
void audio_struct_fused(const float* __restrict__ x_in,
                        const float* __restrict__ gk_in,
                        float* __restrict__ out)
{
    __shared__ __align__(16) float   s_x [XROWS*XS];    // 6720 B
    __shared__ __align__(16) __half2 s_u [UROWS*US];    // 5776 B (ux,uy)
    __shared__ __align__(16) __half2 s_P0[FROWS*FS];    // 5184 B (trace,diff) -> j1 vert
    __shared__ __align__(16) __half2 s_P1[FROWS*FS];    // 5184 B (sxy,tin)    -> j3 vert
    __shared__ __align__(16) __half2 s_P2[FROWS*FS];    // 5184 B (sf,cv)
    __shared__ __align__(16) float   s_tmp[TILE*FS];    // 4608 B ping-pong (h2 or f32)

    const int tx  = threadIdx.x;          // 0..31 (time)
    const int ty  = threadIdx.y;          // 0..7  (freq)
    const int tid = ty * 32 + tx;
    const int t0  = blockIdx.x * TILE;
    const int f0  = blockIdx.y * TILE;
    const int b   = blockIdx.z;

    // 1D gaussian = normalized middle row of the separable 5x5 kernel
    float r0 = gk_in[10], r1 = gk_in[11], r2 = gk_in[12], r3 = gk_in[13], r4 = gk_in[14];
    float winv = __builtin_amdgcn_rcpf(r0 + r1 + r2 + r3 + r4);
    const float w[5] = {r0*winv, r1*winv, r2*winv, r3*winv, r4*winv};
    const __half2 wh2[5] = {pack_h2(w[0],w[0]), pack_h2(w[1],w[1]), pack_h2(w[2],w[2]),
                            pack_h2(w[3],w[3]), pack_h2(w[4],w[4])};

    // paired pk vertical pass: dst[idx] = sum_i w[i]*src[idx + i*FH2] (uint2 lanes)
    auto vpass_pair = [&](const __half2* src, __half2* dst) {
        const uint2* s = (const uint2*)src;
        uint2* d = (uint2*)dst;
        for (int idx = tid; idx < TILE * FH2; idx += 256) {
            __half2 a0 = pack_h2(0.f, 0.f), a1 = a0;
            #pragma unroll
            for (int i = 0; i < 5; ++i) {
                uint2 v = s[idx + i * FH2];
                a0 = __hfma2(wh2[i], *(const __half2*)&v.x, a0);
                a1 = __hfma2(wh2[i], *(const __half2*)&v.y, a1);
            }
            uint2 o; o.x = *(const unsigned*)&a0; o.y = *(const unsigned*)&a1;
            d[idx] = o;
        }
    };

    float acc[6][4];
    #pragma unroll
    for (int k = 0; k < 6; ++k)
        #pragma unroll
        for (int s = 0; s < 4; ++s) acc[k][s] = 0.0f;

    for (int c = 0; c < C_DIM; ++c) {
        __syncthreads();   // protect all LDS reuse across channel iterations

        // ---- Phase A: load x tile + halo 4 (float2, never straddles edges) ----
        const float* xp = x_in + (size_t)(b * C_DIM + c) * F_DIM * T_DIM;
        for (int idx = tid; idx < XROWS * 20; idx += 256) {
            int r  = idx / 20, c2 = idx % 20;
            int gf = f0 + r - 4;
            int gt = t0 + c2 * 2 - 4;
            float2 v = make_float2(0.f, 0.f);
            if ((unsigned)gf < (unsigned)F_DIM && (unsigned)gt < (unsigned)T_DIM)
                v = *(const float2*)(xp + (size_t)gf * T_DIM + gt);
            *(float2*)&s_x[r * XS + c2 * 2] = v;
        }
        __syncthreads();

        // ---- Phase B: (ux,uy) on 38x38; packed fields on 36x36 ----
        for (int idx = tid; idx < UROWS * UROWS; idx += 256) {
            int r = idx / UROWS, cc = idx % UROWS;
            int gfr = f0 + r - 3, gtc = t0 + cc - 3;
            float ux = 0.f, uy = 0.f, trp = 0.f, dfp = 0.f, sxy = 0.f,
                  tin = 0.f, sf = 0.f;
            if ((unsigned)gfr < (unsigned)F_DIM && (unsigned)gtc < (unsigned)T_DIM) {
                const float* xc = &s_x[(r + 1) * XS + (cc + 1)];
                float x00 = xc[-XS-1], x01 = xc[-XS], x02 = xc[-XS+1];
                float x10 = xc[-1],                   x12 = xc[1];
                float x20 = xc[XS-1],  x21 = xc[XS],  x22 = xc[XS+1];
                // cross-correlation (XLA conv does not flip kernels)
                float gfv = ((x20 + 2.f*x21 + x22) - (x00 + 2.f*x01 + x02)) * 0.125f;
                float gtv = ((x02 + 2.f*x12 + x22) - (x00 + 2.f*x10 + x20)) * 0.125f;
                float gte = gtv + EPSF;
                float rh  = __builtin_amdgcn_rsqf(gfv * gfv + gte * gte);
                ux = gte * rh;                 // cos(atan2(gf, gt+eps))
                uy = gfv * rh;                 // sin(atan2(gf, gt+eps))
                float mag = __builtin_amdgcn_sqrtf(gfv * gfv + gtv * gtv + EPSF);
                float vx = mag * ux, vy = mag * uy;
                trp = vx * vx + vy * vy;               // sxx+syy (no cancellation)
                dfp = (vx - vy) * (vx + vy);           // sxx-syy, pre-quantization
                sxy = vx * vy;
                tin = __builtin_amdgcn_rcpf(1.0f + fabsf(gtv));
                sf  = fabsf(gfv);
            }
            s_u[r * US + cc] = pack_h2(ux, uy);
            if (r >= 1 && r < UROWS - 1 && cc >= 1 && cc < UROWS - 1) {
                int fi = (r - 1) * FS + (cc - 1);
                s_P0[fi] = pack_h2(trp, dfp);
                s_P1[fi] = pack_h2(sxy, tin);
                s_P2[fi] = pack_h2(sf, 0.f);   // .y = cv, filled in Phase C
            }
        }
        __syncthreads();

        // ---- Phase C: curv on 36x36 (sobel of ux/uy) -> s_P2.y ----
        for (int idx = tid; idx < FROWS * FROWS; idx += 256) {
            int r = idx / FROWS, cc = idx % FROWS;
            int gfr = f0 + r - 2, gtc = t0 + cc - 2;
            float cv = 0.0f;
            if ((unsigned)gfr < (unsigned)F_DIM && (unsigned)gtc < (unsigned)T_DIM) {
                const __half2* up = &s_u[r * US + cc];
                float2 u00 = __half22float2(up[0]),      u01 = __half22float2(up[1]),       u02 = __half22float2(up[2]);
                float2 u10 = __half22float2(up[US]),                                        u12 = __half22float2(up[US+2]);
                float2 u20 = __half22float2(up[2*US]),   u21 = __half22float2(up[2*US+1]),  u22 = __half22float2(up[2*US+2]);
                float dudx = ((u02.x + 2.f*u12.x + u22.x) - (u00.x + 2.f*u10.x + u20.x)) * 0.125f;
                float dudy = ((u20.x + 2.f*u21.x + u22.x) - (u00.x + 2.f*u01.x + u02.x)) * 0.125f;
                float dvdx = ((u02.y + 2.f*u12.y + u22.y) - (u00.y + 2.f*u10.y + u20.y)) * 0.125f;
                float dvdy = ((u20.y + 2.f*u21.y + u22.y) - (u00.y + 2.f*u01.y + u02.y)) * 0.125f;
                cv = __builtin_amdgcn_sqrtf(dudx*dudx + dudy*dudy + dvdx*dvdx + dvdy*dvdy + EPSF);
            }
            ((__half*)s_P2)[2 * (r * FS + cc) + 1] = __float2half_rn(cv);
        }
        __syncthreads();

        // ====== Phase D: 5 separable jobs; job k horiz fused with job k+1 vert ======
        float trace_s[4], diff_s[4];
        __half2* tmp_h2 = (__half2*)s_tmp;

        // D1: j0 vertical (trace,diff): P0 -> tmp
        vpass_pair(s_P0, tmp_h2);
        __syncthreads();

        // D2: j0 horizontal (f32 accumulate, entropy core) ; j1 vertical: P1 -> P0
        #pragma unroll
        for (int s = 0; s < 4; ++s) {
            int ry = ty + 8 * s;
            float a = 0.f, bv = 0.f;
            #pragma unroll
            for (int j = 0; j < 5; ++j) {
                float2 v = __half22float2(tmp_h2[ry * FS + tx + j]);
                a += w[j] * v.x; bv += w[j] * v.y;
            }
            trace_s[s] = a; diff_s[s] = bv;
        }
        vpass_pair(s_P1, s_P0);
        __syncthreads();

        // D3: j1 horizontal (vxy,tp) + entropy/temporal ; j2 vertical: P2 -> tmp
        #pragma unroll
        for (int s = 0; s < 4; ++s) {
            int ry = ty + 8 * s;
            __half2 a = pack_h2(0.f, 0.f);
            #pragma unroll
            for (int j = 0; j < 5; ++j)
                a = __hfma2(wh2[j], s_P0[ry * FS + tx + j], a);
            float2 v = __half22float2(a);          // (vxy_s, tp)
            float trace = trace_s[s], diff = diff_s[s];
            float disc  = __builtin_amdgcn_sqrtf(
                              fmaxf(diff * diff + 4.f * v.x * v.x, 0.f) + EPSF);
            float l1 = fmaxf(0.5f * (trace + disc), EPSF);
            float l2 = fmaxf(0.5f * (trace - disc), EPSF);
            float inv = __builtin_amdgcn_rcpf(l1 + l2 + EPSF);
            float p1 = l1 * inv, p2 = l2 * inv;
            // v_log_f32 IS log2 — matches reference's ln(p)/ln(2)
            float ent = -(p1 * __builtin_amdgcn_logf(p1 + EPSF)
                        + p2 * __builtin_amdgcn_logf(p2 + EPSF));
            acc[0][s] += 0.5f * clamp01(ent);
            acc[4][s] += 0.5f * clamp01(v.y);
        }
        vpass_pair(s_P2, tmp_h2);
        __syncthreads();

        // D4: j2 horizontal (sp,cvs) ; j3 vertical: u -> P1 (per-elem, odd offset)
        #pragma unroll
        for (int s = 0; s < 4; ++s) {
            int ry = ty + 8 * s;
            __half2 a = pack_h2(0.f, 0.f);
            #pragma unroll
            for (int j = 0; j < 5; ++j)
                a = __hfma2(wh2[j], tmp_h2[ry * FS + tx + j], a);
            float2 v = __half22float2(a);          // (sp, cvs)
            acc[5][s] += 0.5f * clamp01(v.x);
            acc[2][s] += 0.5f * v.y;
        }
        for (int idx = tid; idx < TILE * FS; idx += 256) {
            int r = idx / FS, cc = idx % FS;
            __half2 a = pack_h2(0.f, 0.f);
            #pragma unroll
            for (int i = 0; i < 5; ++i)
                a = __hfma2(wh2[i], s_u[(r + i + 1) * US + (cc + 1)], a);
            s_P1[idx] = a;
        }
        __syncthreads();

        // D5: j3 horizontal (alignment) ; j4 vertical: x^2 -> tmp (f32)
        #pragma unroll
        for (int s = 0; s < 4; ++s) {
            int ry = ty + 8 * s;
            __half2 a = pack_h2(0.f, 0.f);
            #pragma unroll
            for (int j = 0; j < 5; ++j)
                a = __hfma2(wh2[j], s_P1[ry * FS + tx + j], a);
            float2 v = __half22float2(a);          // (ua, va)
            acc[1][s] += 0.5f * clamp01(
                __builtin_amdgcn_sqrtf(v.x * v.x + v.y * v.y + EPSF));
        }
        for (int idx = tid; idx < TILE * FS; idx += 256) {
            int r = idx / FS, cc = idx % FS;
            float a = 0.f;
            #pragma unroll
            for (int i = 0; i < 5; ++i) {
                float xv = s_x[(r + i + 2) * XS + (cc + 2)];
                a += w[i] * xv * xv;
            }
            s_tmp[idx] = a;
        }
        __syncthreads();

        // D6: j4 horizontal (le) + harmonic epilogue
        #pragma unroll
        for (int s = 0; s < 4; ++s) {
            int ry = ty + 8 * s;
            float le = 0.f;
            #pragma unroll
            for (int j = 0; j < 5; ++j)
                le += w[j] * s_tmp[ry * FS + tx + j];
            float xm  = s_x[(ry + 1) * XS + tx + 4];
            float x0v = s_x[(ry + 4) * XS + tx + 4];
            float xpv = s_x[(ry + 7) * XS + tx + 4];
            float harm = fabsf(2.f * x0v - xm - xpv);
            acc[3][s] += 0.5f * clamp01(harm * __builtin_amdgcn_rcpf(le + EPSF));
        }
        // loop-top __syncthreads() protects reuse for channel 1
    }

    // ---- write 6 output planes, coalesced ----
    const size_t plane = (size_t)B_DIM * F_DIM * T_DIM;
    const size_t base  = (size_t)b * F_DIM * T_DIM + (size_t)f0 * T_DIM + t0 + tx;
    #pragma unroll
    for (int k = 0; k < 6; ++k)
        #pragma unroll
        for (int s = 0; s < 4; ++s)
            out[k * plane + base + (size_t)(ty + 8 * s) * T_DIM] = acc[k][s];
}

extern "C" void kernel_launch(void* const* d_in, const int* in_sizes, int n_in,
                              void* d_out, int out_size, void* d_ws, size_t ws_size,
                              hipStream_t stream) {
    const float* x  = (const float*)d_in[0];
    const float* gk = (const float*)d_in[1];
    float* out = (float*)d_out;
    dim3 grid(T_DIM / TILE, F_DIM / TILE, B_DIM);   // 64 x 8 x 8 = 4096 blocks
    dim3 block(32, 8);                              // 256 threads = 4 waves
    audio_struct_fused<<<grid, block, 0, stream>>>(x, gk, out);
}